// Round 19
// baseline (184.083 us; speedup 1.0000x reference)
//
#include <hip/hip_runtime.h>
#include <hip/hip_bf16.h>
#include <stdint.h>

#define DEVI static __device__ __forceinline__

typedef __attribute__((ext_vector_type(4))) float f32x4;
typedef __attribute__((ext_vector_type(4))) unsigned int u32x4;
typedef __attribute__((ext_vector_type(8))) short bf16x8;
typedef unsigned short u16;
typedef unsigned int u32;
typedef unsigned long long u64;

// B=16, N=4096, C=384, H=8, D=48
#define BB 16
#define NN 4096
#define CC 384
#define HH 8
#define DD 48

DEVI u16 f2bf(float f) {
  union { float f; u32 u; } c; c.f = f;
  u32 u = c.u;
  u32 r = (u + 0x7FFFu + ((u >> 16) & 1u)) >> 16;
  return (u16)r;
}
DEVI float bf2f(u16 h) {
  union { float f; u32 u; } c; c.u = ((u32)h) << 16;
  return c.f;
}
DEVI void stage8(u16* dst, const float* src) {
  const f32x4 a = *(const f32x4*)(src);
  const f32x4 b = *(const f32x4*)(src + 4);
  union { bf16x8 v; u16 u[8]; } o;
  o.u[0] = f2bf(a[0]); o.u[1] = f2bf(a[1]); o.u[2] = f2bf(a[2]); o.u[3] = f2bf(a[3]);
  o.u[4] = f2bf(b[0]); o.u[5] = f2bf(b[1]); o.u[6] = f2bf(b[2]); o.u[7] = f2bf(b[3]);
  *(bf16x8*)dst = o.v;
}

typedef const __attribute__((address_space(1))) void* gas_ptr;
typedef __attribute__((address_space(3))) void* las_ptr;
DEVI void gload16(const void* g, void* l) {
  __builtin_amdgcn_global_load_lds((gas_ptr)g, (las_ptr)l, 16, 0, 0);
}

// ============================================================================
// conv_fused: bid<3072 -> x f32->bf16 (4 chunks/block); bid>=3072 -> weight
// converts / cw transpose / bias fuse.
// ============================================================================
__global__ __launch_bounds__(256)
void conv_fused(const float* __restrict__ x, u16* __restrict__ xb,
                const float* __restrict__ wp, const float* __restrict__ wq,
                const float* __restrict__ wkv, const float* __restrict__ cw,
                const float* __restrict__ bq, const float* __restrict__ bkv,
                const float* __restrict__ cb, u16* __restrict__ wpb,
                u16* __restrict__ wtopb, u16* __restrict__ cwTb,
                float* __restrict__ bf_) {
  __shared__ u32 LtT[64 * 33];
  const int bid = blockIdx.x;
  const int t = threadIdx.x;
  if (bid < 3072) {                   // x convert: 4 contiguous chunk passes
#pragma unroll
    for (int pass = 0; pass < 4; ++pass) {
      const size_t i = ((size_t)(bid * 4 + pass) * 256 + t) * 8;
      u16 tmp[8];
      stage8(tmp, x + i);
      *(bf16x8*)(xb + i) = *(bf16x8*)tmp;
    }
    return;
  }
  const int blk = bid - 3072;         // 0..611
  if (blk < 288) {                    // weight converts
    const float* src; u16* dst; int base;
    if (blk < 72)       { src = wp;  dst = wpb;             base = blk; }
    else if (blk < 144) { src = wq;  dst = wtopb;           base = blk - 72; }
    else                { src = wkv; dst = wtopb + CC * CC; base = blk - 144; }
    const int i = base * 256 + t;
    u16 tmp[8];
    stage8(tmp, src + (size_t)i * 8);
    *(bf16x8*)(dst + (size_t)i * 8) = *(bf16x8*)tmp;
  } else if (blk < 324) {             // transpose_cw
    const int blk2 = blk - 288;
    const int m0 = (blk2 / 6) * 64, c0 = (blk2 % 6) * 64;
    const int cl = (t & 15) * 4;
    const int mp = t >> 4;
#pragma unroll
    for (int pass = 0; pass < 2; ++pass) {
      const int w = mp + pass * 16;
      const int m = w * 2;
      const float* s0 = &cw[(size_t)(m0 + m) * CC + c0 + cl];
      const f32x4 a = *(const f32x4*)s0;
      const f32x4 bv = *(const f32x4*)(s0 + CC);
#pragma unroll
      for (int i = 0; i < 4; ++i)
        LtT[(cl + i) * 33 + w] = (u32)f2bf(a[i]) | ((u32)f2bf(bv[i]) << 16);
    }
    __syncthreads();
#pragma unroll
    for (int pass = 0; pass < 2; ++pass) {
      const int v = pass * 256 + t;
      const int c = v >> 3, mg = v & 7;
      union { bf16x8 o; u32 q[4]; } u;
#pragma unroll
      for (int r = 0; r < 4; ++r) u.q[r] = LtT[c * 33 + mg * 4 + r];
      *(bf16x8*)&cwTb[(size_t)(c0 + c) * CC + m0 + mg * 8] = u.o;
    }
  } else {                            // bias_fuse
    const int o = (blk - 324) * 4 + (t >> 6);
    const int lane = t & 63;
    const float* wrow;
    float b0;
    if (o < CC) { wrow = wq + (size_t)o * CC;        b0 = bq[o]; }
    else        { wrow = wkv + (size_t)(o - CC) * CC; b0 = bkv[o - CC]; }
    float s = 0.f;
    for (int m = lane; m < CC; m += 64) s += wrow[m] * cb[m];
#pragma unroll
    for (int off = 32; off; off >>= 1) s += __shfl_xor(s, off, 64);
    if (lane == 0) bf_[o] = b0 + s;
  }
}

// ============================================================================
// trans_colsum: bid<27 -> weight GEMMs; 27..1562 -> transpose tiles
// (nt-fastest); 1563+ -> colsum partials.
// ============================================================================
__global__ __launch_bounds__(256)
void trans_colsum(const u16* __restrict__ xb, u16* __restrict__ xbT,
                  float* __restrict__ sxp, const u16* __restrict__ wtopb,
                  const u16* __restrict__ cwTb, u16* __restrict__ Wf,
                  u16* __restrict__ UvT) {
  __shared__ __align__(16) char smem[33280];
  const int bid = blockIdx.x;
  const int t = threadIdx.x;
  if (bid < 27) {                     // weight GEMMs: Wf = wtop@cw ; UvT
    u16* smemu = (u16*)smem;          // uses 32768 B
    int wb = bid;
    const u16 *A, *W; u16* C;
    if (wb < 18) { A = wtopb; W = cwTb; C = Wf; }
    else { wb -= 18; A = cwTb; W = wtopb + 2 * CC * CC; C = UvT; }
    const int bn = wb % 3, bm = wb / 3;
    const int wid = t >> 6, lane = t & 63;
    const int wr = wid >> 1, wc = wid & 1;
    const int row0 = bm * 128, col0 = bn * 128;
    const int lrow = lane & 15;
    const int lswz = (lane & 7) << 3;
    const int arow = t >> 3;
    const int scol = ((t & 7) ^ ((t >> 3) & 7)) * 8;
    const u16* Ag = A + (size_t)(row0 + arow) * CC + scol;
    const u16* Wg = W + (size_t)(col0 + arow) * CC + scol;
    u16* As = smemu;
    u16* Bs = smemu + 8192;
    f32x4 acc[4][4] = {};
    for (int kt = 0; kt < 6; ++kt) {
      __syncthreads();
      const int k0 = kt * 64;
#pragma unroll
      for (int it = 0; it < 4; ++it) {
        gload16(Ag + (size_t)(it * 32) * CC + k0, As + t * 8 + it * 2048);
        gload16(Wg + (size_t)(it * 32) * CC + k0, Bs + t * 8 + it * 2048);
      }
      __syncthreads();
#pragma unroll
      for (int kk = 0; kk < 2; ++kk) {
        const int lk = (kk * 32 + (lane >> 4) * 8) ^ lswz;
        bf16x8 af[4], bf4[4];
#pragma unroll
        for (int i = 0; i < 4; ++i)
          af[i] = *(const bf16x8*)&As[(wr * 64 + i * 16 + lrow) * 64 + lk];
#pragma unroll
        for (int j = 0; j < 4; ++j)
          bf4[j] = *(const bf16x8*)&Bs[(wc * 64 + j * 16 + lrow) * 64 + lk];
#pragma unroll
        for (int i = 0; i < 4; ++i)
#pragma unroll
          for (int j = 0; j < 4; ++j)
            acc[i][j] = __builtin_amdgcn_mfma_f32_16x16x32_bf16(af[i], bf4[j], acc[i][j], 0, 0, 0);
      }
    }
    const int lr = (lane >> 4) * 4;
#pragma unroll
    for (int i = 0; i < 4; ++i)
#pragma unroll
      for (int j = 0; j < 4; ++j) {
        const int ccol = col0 + wc * 64 + j * 16 + lrow;
#pragma unroll
        for (int r = 0; r < 4; ++r)
          C[(size_t)(row0 + wr * 64 + i * 16 + lr + r) * CC + ccol] =
              f2bf(acc[i][j][r]);
      }
    return;
  }
  if (bid < 1563) {                   // transpose tile (32c x 512n), nt-fastest
    u32* LtT = (u32*)smem;            // [32][260]
    const int tb = bid - 27;
    const int nt = tb % 8, ct = (tb / 8) % 12, b = tb / 96;
    const int n0 = nt * 512, c0 = ct * 32;
    const int coct = t & 3, c = coct * 8;
    const int q = t >> 2;
    const int swzw = coct << 3;
#pragma unroll
    for (int p = 0; p < 4; ++p) {
      const int npair = q + p * 64;
      const int n = 2 * npair;
      const u16* s0 = &xb[((size_t)(b * NN + n0 + n)) * CC + c0 + c];
      union { bf16x8 v; u16 e[8]; } ua, ub;
      ua.v = *(const bf16x8*)s0;
      ub.v = *(const bf16x8*)(s0 + CC);
      const int npw = npair ^ swzw;
#pragma unroll
      for (int i = 0; i < 8; ++i)
        LtT[(c + i) * 260 + npw] = (u32)ua.e[i] | ((u32)ub.e[i] << 16);
    }
    __syncthreads();
#pragma unroll
    for (int p = 0; p < 8; ++p) {
      const int id = p * 256 + t;
      const int cc2 = id >> 6, ng = id & 63;
      const int swz2 = ((cc2 >> 3) & 3) << 3;
      union { u32x4 q4; bf16x8 o; } u;
      u.q4 = *(const u32x4*)&LtT[cc2 * 260 + ((ng * 4) ^ swz2)];
      *(bf16x8*)&xbT[((size_t)(b * CC + c0 + cc2)) * NN + n0 + ng * 8] = u.o;
    }
  } else {                            // colsum partial over n-quarter p
    float (*red)[8] = (float(*)[8])smem;       // [256][8]
    const int k = bid - 1563;         // 0..383
    const int p = k & 3, k2 = k >> 2;
    const int c0 = (k2 % 6) * 64, b = k2 / 6;
    const int c8 = t & 7, ns = t >> 3;
    const u16* src = xb + (size_t)b * NN * CC + (size_t)(p * 1024) * CC +
                     c0 + c8 * 8;
    float a[8] = {};
    for (int it = 0; it < 32; ++it) {
      const bf16x8 v = *(const bf16x8*)(src + (size_t)(ns + 32 * it) * CC);
#pragma unroll
      for (int r = 0; r < 8; ++r) a[r] += bf2f((u16)v[r]);
    }
#pragma unroll
    for (int r = 0; r < 8; ++r) red[t][r] = a[r];
    __syncthreads();
    if (t < 64) {
      const int c8o = t >> 3, e = t & 7;
      float s = 0.f;
#pragma unroll
      for (int n2 = 0; n2 < 32; ++n2) s += red[c8o + 8 * n2][e];
      sxp[(size_t)(p * 16 + b) * CC + c0 + c8o * 8 + e] = s;
    }
  }
}

// ============================================================================
// Generic GEMM: C[M,N](+p partials) = A[M,K-slice] @ W[N,K-slice]^T (+bias)
// 512 threads / 8 waves, dbuf issue-early/wait-late, T2 swizzle.
// BN2 (128|64): block tile N. BN2=64 -> 48KB LDS -> 3 blocks/CU (was 2):
// +50% resident waves to hide the per-K-tile drain (tail GEMMs, K=384).
// TRI: 6 upper tiles (BN2=128 only). SWZ: XCD swizzle. ORD: bm-fastest.
// ============================================================================
template<typename OT, int BIASMODE, int TRI = 0, int SWZ = 1, int ORD = 0,
         int BN2 = 128>
__global__ __launch_bounds__(512)
void gemm_f(const u16* __restrict__ A, const u16* __restrict__ W,
            const float* __restrict__ bias, OT* __restrict__ C,
            int M, int N, int K, int klen, int nbn, int nbm, int tpb,
            long sA, long sW, long sC, long sCp, long sBias) {
  constexpr int BK = 64;
  constexpr int NJ = BN2 / 64;                  // wave col-frags (2 or 1)
  constexpr int BSZ = BN2 * 64;                 // B-tile u16
  constexpr int BUF = 8192 + BSZ;               // per-buffer u16
  __shared__ __align__(16) u16 smem[2 * BUF];   // 64KB (128) / 48KB (64)

  const int nx = gridDim.x;
  const int lin = blockIdx.x;
  const int lin2 = SWZ ? (lin & 7) * (nx >> 3) + (lin >> 3) : lin;
  const int b = lin2 / tpb;
  int t2 = lin2 % tpb;
  int bn, bm, p;
  if constexpr (TRI) {
    const int tl = t2 % 6; p = t2 / 6;
    bm = tl < 3 ? 0 : (tl < 5 ? 1 : 2);
    bn = tl < 3 ? tl : (tl < 5 ? tl - 2 : 2);
  } else if constexpr (ORD) {
    bm = t2 % nbm; t2 /= nbm;
    bn = t2 % nbn;
    p = t2 / nbn;
  } else {
    bn = t2 % nbn; t2 /= nbn;
    bm = t2 % nbm;
    p = t2 / nbm;
  }
  A += (size_t)b * sA; W += (size_t)b * sW;
  C += (size_t)b * sC + (size_t)p * sCp;
  if (BIASMODE) bias += (size_t)b * sBias;

  const int t = threadIdx.x;
  const int wid = t >> 6, lane = t & 63;
  const int wr = wid >> 2, wc = wid & 3;        // 2 x 4 waves, 64 x BN2/4
  const int row0 = bm * 128, col0 = bn * BN2;
  const int lrow = lane & 15;
  const int lswz = (lane & 7) << 3;
  const int kstart = p * klen;

  const int arow = t >> 3;                       // 0..63
  const int scol = ((t & 7) ^ ((t >> 3) & 7)) * 8;   // inverse-swizzled source
  const u16* Ag = A + (size_t)(row0 + arow) * K + scol;
  const u16* Wg = W + (size_t)(col0 + arow) * K + scol;

  f32x4 acc[4][NJ] = {};
  const int NT = klen >> 6;

  auto stage = [&](int buf, int kt) {
    u16* Al = smem + buf * BUF + t * 8;
    u16* Bl = smem + buf * BUF + 8192 + t * 8;
    const int k0 = kstart + kt * BK;
#pragma unroll
    for (int it = 0; it < 2; ++it) {
      gload16(Ag + (size_t)(it * 64) * K + k0, Al + it * 4096);
      if (it < NJ) gload16(Wg + (size_t)(it * 64) * K + k0, Bl + it * 4096);
    }
  };

  stage(0, 0);
  __syncthreads();                 // drain tile 0
  int cur = 0;
  for (int kt = 0; kt < NT; ++kt) {
    if (kt + 1 < NT) stage(cur ^ 1, kt + 1);     // issue-early (overlaps MFMA)
    const u16* As = smem + cur * BUF;
    const u16* Bs = smem + cur * BUF + 8192;
#pragma unroll
    for (int kk = 0; kk < 2; ++kk) {
      const int lk = (kk * 32 + (lane >> 4) * 8) ^ lswz;
      bf16x8 af[4], bfv[NJ];
#pragma unroll
      for (int i = 0; i < 4; ++i)
        af[i] = *(const bf16x8*)&As[(wr * 64 + i * 16 + lrow) * BK + lk];
#pragma unroll
      for (int j = 0; j < NJ; ++j)
        bfv[j] = *(const bf16x8*)&Bs[(wc * (BN2 / 4) + j * 16 + lrow) * BK + lk];
#pragma unroll
      for (int i = 0; i < 4; ++i)
#pragma unroll
        for (int j = 0; j < NJ; ++j)
          acc[i][j] = __builtin_amdgcn_mfma_f32_16x16x32_bf16(af[i], bfv[j], acc[i][j], 0, 0, 0);
    }
    __syncthreads();               // wait-late: drains next tile's loads + LDS reads
    cur ^= 1;
  }

  const int lr = (lane >> 4) * 4;
  if constexpr (sizeof(OT) == 2) {
    u16* Ct = smem;                 // [128][BN2+4]
#pragma unroll
    for (int i = 0; i < 4; ++i)
#pragma unroll
      for (int j = 0; j < NJ; ++j) {
        const int ccol = wc * (BN2 / 4) + j * 16 + lrow;
        float bv = 0.f;
        if constexpr (BIASMODE == 1) bv = bias[col0 + ccol];
#pragma unroll
        for (int r = 0; r < 4; ++r) {
          const int rrow = wr * 64 + i * 16 + lr + r;
          float b2 = bv;
          if constexpr (BIASMODE == 2) b2 = bias[row0 + rrow];
          Ct[rrow * (BN2 + 4) + ccol] = f2bf(acc[i][j][r] + b2);
        }
      }
    __syncthreads();
    constexpr int CPR = BN2 / 8;    // 8-u16 chunks per row
#pragma unroll
    for (int it = 0; it < 128 * CPR / 512; ++it) {
      const int id = it * 512 + t;
      const int row = id / CPR, c16 = (id % CPR) * 8;
      *(bf16x8*)((u16*)C + (size_t)(row0 + row) * N + col0 + c16) =
          *(const bf16x8*)&Ct[row * (BN2 + 4) + c16];
    }
  } else {
    const int orow = row0 + wr * 64, ocol = col0 + wc * (BN2 / 4);
#pragma unroll
    for (int i = 0; i < 4; ++i)
#pragma unroll
      for (int j = 0; j < NJ; ++j) {
        const int cc2 = ocol + j * 16 + lrow;
        float bv = 0.f;
        if constexpr (BIASMODE == 1) bv = bias[cc2];
#pragma unroll
        for (int r = 0; r < 4; ++r) {
          const int rr = orow + i * 16 + lr + r;
          float b2 = bv;
          if constexpr (BIASMODE == 2) b2 = bias[rr];
          C[(size_t)rr * N + cc2] = acc[i][j][r] + b2;
        }
      }
  }
}

// ============================================================================
// red_proj: blk<576 -> reduceG tile (coalesced + mirrored);
// blk>=576 -> proj_sx (P[b][o] = Wf[o]@sx[b], 48 blocks x 256 thr).
// ============================================================================
__global__ __launch_bounds__(256)
void red_proj(const float* __restrict__ Gp, u16* __restrict__ Gbf,
              const u16* __restrict__ Wf, const float* __restrict__ sxp,
              float* __restrict__ P) {
  __shared__ __align__(16) char smemc[16640];
  const int blk = blockIdx.x;
  const int t = threadIdx.x;
  if (blk < 576) {                    // reduceG
    float* lt = (float*)smemc;        // [64][65]
    const int tile = blk % 36, b = blk / 36;
    const int ti = tile / 6, tj = tile % 6;
    const bool mir = (ti >> 1) > (tj >> 1);
    const int si = mir ? tj : ti, sj = mir ? ti : tj;
    const float* src = Gp + (size_t)b * 4 * 147456;
    u16* dst = Gbf + (size_t)b * 147456;
    const int r4 = t >> 4, c4 = (t & 15) * 4;
#pragma unroll
    for (int pass = 0; pass < 4; ++pass) {
      const int r = pass * 16 + r4;
      const size_t off = (size_t)(si * 64 + r) * CC + sj * 64 + c4;
      f32x4 s = *(const f32x4*)(src + off);
      s += *(const f32x4*)(src + 147456 + off);
      s += *(const f32x4*)(src + 2 * 147456 + off);
      s += *(const f32x4*)(src + 3 * 147456 + off);
      if (!mir) {
        union { u64 q; u16 e[4]; } o;
        o.e[0] = f2bf(s[0]); o.e[1] = f2bf(s[1]);
        o.e[2] = f2bf(s[2]); o.e[3] = f2bf(s[3]);
        *(u64*)&dst[(size_t)(ti * 64 + r) * CC + tj * 64 + c4] = o.q;
      } else {
#pragma unroll
        for (int k = 0; k < 4; ++k) lt[r * 65 + c4 + k] = s[k];
      }
    }
    if (mir) {
      __syncthreads();
#pragma unroll
      for (int pass = 0; pass < 4; ++pass) {
        const int i = pass * 16 + r4;
        union { u64 q; u16 e[4]; } o;
#pragma unroll
        for (int k = 0; k < 4; ++k) o.e[k] = f2bf(lt[(c4 + k) * 65 + i]);
        *(u64*)&dst[(size_t)(ti * 64 + i) * CC + tj * 64 + c4] = o.q;
      }
    }
  } else {                            // proj_sx: 48 blocks (b, o-segment)
    float* sl = (float*)smemc;        // [384]
    const int blk2 = blk - 576;
    const int b = blk2 / 3, seg = blk2 % 3;
    for (int i = t; i < CC; i += 256)
      sl[i] = sxp[(size_t)b * CC + i] + sxp[(size_t)(16 + b) * CC + i] +
              sxp[(size_t)(32 + b) * CC + i] + sxp[(size_t)(48 + b) * CC + i];
    __syncthreads();
    const int o = seg * 256 + t;
    if (o < 768) {
      float acc = 0.f;
      const u16* wr = Wf + (size_t)o * CC;
      for (int c8 = 0; c8 < CC; c8 += 8) {
        const bf16x8 w = *(const bf16x8*)(wr + c8);
#pragma unroll
        for (int r = 0; r < 8; ++r) acc += bf2f((u16)w[r]) * sl[c8 + r];
      }
      P[b * 768 + o] = acc;
    }
  }
}

// ============================================================================
// s_softmax: per (b,h): S = M1_h @ Uk_h^T + rank-1 terms, *N^-0.5, softmax;
// AU = attn @ Uv_h -> AUb rows (i*8+h); rbias = attn @ bv'
// ============================================================================
__global__ __launch_bounds__(256)
void s_softmax(const u16* __restrict__ M1g, const u16* __restrict__ Wf,
               const float* __restrict__ bf_, const float* __restrict__ P,
               const u16* __restrict__ UvT, u16* __restrict__ AUb,
               float* __restrict__ rbias) {
  __shared__ float Sf[48 * 52];
  __shared__ __align__(16) u16 att[48 * 56];
  const int bh = blockIdx.x, b = bh >> 3, h = bh & 7;
  const int t = threadIdx.x, wid = t >> 6, lane = t & 63;
  const int lrow = lane & 15, lkq = lane >> 4;

  if (wid < 3) {
    f32x4 acc[3] = {};
    const u16* Arow = M1g + (size_t)b * 147456 + (size_t)(h * 48 + wid * 16 + lrow) * CC;
    const u16* Brow = Wf + (size_t)(CC + h * 48) * CC;    // Uk
    for (int ks = 0; ks < 12; ++ks) {
      const int k = ks * 32 + lkq * 8;
      const bf16x8 af = *(const bf16x8*)(Arow + k);
#pragma unroll
      for (int j = 0; j < 3; ++j) {
        const bf16x8 bfr = *(const bf16x8*)(Brow + (size_t)(j * 16 + lrow) * CC + k);
        acc[j] = __builtin_amdgcn_mfma_f32_16x16x32_bf16(af, bfr, acc[j], 0, 0, 0);
      }
    }
    const int lr = lkq * 4;
#pragma unroll
    for (int j = 0; j < 3; ++j)
#pragma unroll
      for (int r = 0; r < 4; ++r)
        Sf[(wid * 16 + lr + r) * 52 + j * 16 + lrow] = acc[j][r];
  }
  __syncthreads();

  if (t < 48) {
    const float bi = bf_[h * 48 + t];
    const float pq = P[b * 768 + h * 48 + t];
    float row[48];
    float mx = -1e30f;
#pragma unroll
    for (int j = 0; j < 48; ++j) {
      const float g = bf_[CC + h * 48 + j];
      const float pk = P[b * 768 + CC + h * 48 + j];
      const float s = (Sf[t * 52 + j] + bi * pk + pq * g + 4096.f * bi * g) * 0.015625f;
      row[j] = s;
      mx = fmaxf(mx, s);
    }
    float sum = 0.f;
#pragma unroll
    for (int j = 0; j < 48; ++j) { row[j] = __expf(row[j] - mx); sum += row[j]; }
    const float inv = 1.f / sum;
    float rb = 0.f;
#pragma unroll
    for (int j = 0; j < 48; ++j) {
      const float a = row[j] * inv;
      att[t * 56 + j] = f2bf(a);
      rb += a * bf_[2 * CC + h * 48 + j];
    }
#pragma unroll
    for (int j = 48; j < 56; ++j) att[t * 56 + j] = 0;
    rbias[b * CC + t * 8 + h] = rb;
  }
  __syncthreads();

  f32x4 acc[3][6] = {};
  const u16* Vbase = UvT + h * 48;
  const bf16x8 z = {};
#pragma unroll
  for (int kk = 0; kk < 2; ++kk) {
    const int k = kk * 32 + lkq * 8;
    bf16x8 af[3];
#pragma unroll
    for (int i = 0; i < 3; ++i) {
      af[i] = *(const bf16x8*)&att[(i * 16 + lrow) * 56 + k];
      if (k >= 48) af[i] = z;
    }
#pragma unroll
    for (int ct = 0; ct < 6; ++ct) {
      const int c = wid * 96 + ct * 16 + lrow;
      bf16x8 bfr = *(const bf16x8*)(Vbase + (size_t)c * CC + k);
      if (k >= 48) bfr = z;
#pragma unroll
      for (int i = 0; i < 3; ++i)
        acc[i][ct] = __builtin_amdgcn_mfma_f32_16x16x32_bf16(af[i], bfr, acc[i][ct], 0, 0, 0);
    }
  }
  const int lr = lkq * 4;
#pragma unroll
  for (int i = 0; i < 3; ++i)
#pragma unroll
    for (int ct = 0; ct < 6; ++ct) {
      const int c = wid * 96 + ct * 16 + lrow;
#pragma unroll
      for (int r = 0; r < 4; ++r) {
        const int ii = i * 16 + lr + r;
        AUb[(size_t)b * 147456 + (size_t)(ii * 8 + h) * CC + c] = f2bf(acc[i][ct][r]);
      }
    }
}

// ============================================================================
extern "C" void kernel_launch(void* const* d_in, const int* in_sizes, int n_in,
                              void* d_out, int out_size, void* d_ws, size_t ws_size,
                              hipStream_t stream) {
  const float* x      = (const float*)d_in[0];
  const float* conv_w = (const float*)d_in[1];
  const float* conv_b = (const float*)d_in[2];
  const float* wq     = (const float*)d_in[3];
  const float* bq     = (const float*)d_in[4];
  const float* wkv    = (const float*)d_in[5];
  const float* bkv    = (const float*)d_in[6];
  const float* wp     = (const float*)d_in[7];
  const float* bp     = (const float*)d_in[8];
  float* y = (float*)d_out;

  char* ws = (char*)d_ws;
  u16*   Wf    = (u16*)(ws + 0);              //   884,736 (rows 768+ unused)
  float* bf_   = (float*)(ws + 884736);       //     4,608
  u16*   wpb   = (u16*)(ws + 889344);         //   294,912
  u16*   UvT   = (u16*)(ws + 1184256);        //   294,912
  float* P     = (float*)(ws + 1503744);      //    49,152
  float* rb    = (float*)(ws + 1552896);      //    24,576
  u16*   M1g   = (u16*)(ws + 1577472);        // 4,718,592
  u16*   Gbf   = (u16*)(ws + 6296064);        // 4,718,592
  u16*   AUb   = (u16*)(ws + 11014656);       // 4,718,592
  float* Gpart = (float*)(ws + 15733248);     // 37,748,736
  float* sxp   = Gpart;                       // 98,304 (dead before gram)
  u16*   wtopb = (u16*)(ws + 53481984);       //   884,736  [wq;wkv] bf16
  u16*   cwTb  = (u16*)(ws + 54366720);       //   294,912  cw^T bf16
  u16*   xb    = (u16*)(ws + 54661632);       // 50,331,648
  u16*   xbT   = (u16*)(ws + 104993280);      // 50,331,648 (dead after gram)
  u16*   R     = xbT;                         // aliases xbT
  // total ws use: 155,324,928 B

  // K1: x->bf16 + all weight prep (merged)
  conv_fused<<<dim3(3684), dim3(256), 0, stream>>>(
      x, xb, wp, wq, wkv, conv_w, bq, bkv, conv_b, wpb, wtopb, cwTb, bf_);
  // K2: weight GEMMs (27) + xb transpose (1536, nt-fastest) + colsum (384)
  trans_colsum<<<dim3(1947), dim3(256), 0, stream>>>(
      xb, xbT, sxp, wtopb, cwTb, Wf, UvT);
  // K3: Gram partials (symmetric: 6 upper tiles), split-K 4
  gemm_f<float, 0, 1><<<dim3(384), dim3(512), 0, stream>>>(
      xbT, xbT, nullptr, Gpart, CC, CC, NN, 1024, 3, 3, 24,
      (long)CC * NN, (long)CC * NN, 4L * 147456, 147456, 0);
  // K4: reduceG (576) + proj_sx (48) merged
  red_proj<<<dim3(624), dim3(256), 0, stream>>>(Gpart, Gbf, Wf, sxp, P);
  // K5: M1g[b] = Uq @ Gx_b
  gemm_f<u16, 0><<<dim3(144), dim3(512), 0, stream>>>(
      Wf, Gbf, nullptr, M1g, CC, CC, CC, CC, 3, 3, 9,
      0, 147456, 147456, 0, 0);
  // K6: S + softmax + AU
  s_softmax<<<dim3(128), dim3(256), 0, stream>>>(M1g, Wf, bf_, P, UvT, AUb, rb);
  // K7: R[b] = AUb[b] @ xb_b^T + rbias; BN2=64 (3 blocks/CU), ORD=1
  gemm_f<u16, 2, 0, 1, 1, 64><<<dim3(3072), dim3(512), 0, stream>>>(
      AUb, xb, rb, R, CC, NN, CC, CC, 64, 3, 192,
      147456, (long)NN * CC, (long)NN * CC, 0, CC);
  // K8: y = R @ wpb^T + bp; BN2=64
  gemm_f<float, 1, 0, 1, 0, 64><<<dim3(3072), dim3(512), 0, stream>>>(
      R, wpb, bp, y, BB * NN, CC, CC, CC, 6, 512, 3072,
      0, 0, 0, 0, 0);
}

// Round 20
// 181.396 us; speedup vs baseline: 1.0148x; 1.0148x over previous
//
#include <hip/hip_runtime.h>
#include <hip/hip_bf16.h>
#include <stdint.h>

#define DEVI static __device__ __forceinline__

typedef __attribute__((ext_vector_type(4))) float f32x4;
typedef __attribute__((ext_vector_type(4))) unsigned int u32x4;
typedef __attribute__((ext_vector_type(8))) short bf16x8;
typedef unsigned short u16;
typedef unsigned int u32;
typedef unsigned long long u64;

// B=16, N=4096, C=384, H=8, D=48
#define BB 16
#define NN 4096
#define CC 384
#define HH 8
#define DD 48

DEVI u16 f2bf(float f) {
  union { float f; u32 u; } c; c.f = f;
  u32 u = c.u;
  u32 r = (u + 0x7FFFu + ((u >> 16) & 1u)) >> 16;
  return (u16)r;
}
DEVI float bf2f(u16 h) {
  union { float f; u32 u; } c; c.u = ((u32)h) << 16;
  return c.f;
}
DEVI void stage8(u16* dst, const float* src) {
  const f32x4 a = *(const f32x4*)(src);
  const f32x4 b = *(const f32x4*)(src + 4);
  union { bf16x8 v; u16 u[8]; } o;
  o.u[0] = f2bf(a[0]); o.u[1] = f2bf(a[1]); o.u[2] = f2bf(a[2]); o.u[3] = f2bf(a[3]);
  o.u[4] = f2bf(b[0]); o.u[5] = f2bf(b[1]); o.u[6] = f2bf(b[2]); o.u[7] = f2bf(b[3]);
  *(bf16x8*)dst = o.v;
}

typedef const __attribute__((address_space(1))) void* gas_ptr;
typedef __attribute__((address_space(3))) void* las_ptr;
DEVI void gload16(const void* g, void* l) {
  __builtin_amdgcn_global_load_lds((gas_ptr)g, (las_ptr)l, 16, 0, 0);
}

// ============================================================================
// conv_fused: bid<3072 -> x f32->bf16 (4 chunks/block); bid>=3072 -> weight
// converts / cw transpose / bias fuse.
// ============================================================================
__global__ __launch_bounds__(256)
void conv_fused(const float* __restrict__ x, u16* __restrict__ xb,
                const float* __restrict__ wp, const float* __restrict__ wq,
                const float* __restrict__ wkv, const float* __restrict__ cw,
                const float* __restrict__ bq, const float* __restrict__ bkv,
                const float* __restrict__ cb, u16* __restrict__ wpb,
                u16* __restrict__ wtopb, u16* __restrict__ cwTb,
                float* __restrict__ bf_) {
  __shared__ u32 LtT[64 * 33];
  const int bid = blockIdx.x;
  const int t = threadIdx.x;
  if (bid < 3072) {                   // x convert: 4 contiguous chunk passes
#pragma unroll
    for (int pass = 0; pass < 4; ++pass) {
      const size_t i = ((size_t)(bid * 4 + pass) * 256 + t) * 8;
      u16 tmp[8];
      stage8(tmp, x + i);
      *(bf16x8*)(xb + i) = *(bf16x8*)tmp;
    }
    return;
  }
  const int blk = bid - 3072;         // 0..611
  if (blk < 288) {                    // weight converts
    const float* src; u16* dst; int base;
    if (blk < 72)       { src = wp;  dst = wpb;             base = blk; }
    else if (blk < 144) { src = wq;  dst = wtopb;           base = blk - 72; }
    else                { src = wkv; dst = wtopb + CC * CC; base = blk - 144; }
    const int i = base * 256 + t;
    u16 tmp[8];
    stage8(tmp, src + (size_t)i * 8);
    *(bf16x8*)(dst + (size_t)i * 8) = *(bf16x8*)tmp;
  } else if (blk < 324) {             // transpose_cw
    const int blk2 = blk - 288;
    const int m0 = (blk2 / 6) * 64, c0 = (blk2 % 6) * 64;
    const int cl = (t & 15) * 4;
    const int mp = t >> 4;
#pragma unroll
    for (int pass = 0; pass < 2; ++pass) {
      const int w = mp + pass * 16;
      const int m = w * 2;
      const float* s0 = &cw[(size_t)(m0 + m) * CC + c0 + cl];
      const f32x4 a = *(const f32x4*)s0;
      const f32x4 bv = *(const f32x4*)(s0 + CC);
#pragma unroll
      for (int i = 0; i < 4; ++i)
        LtT[(cl + i) * 33 + w] = (u32)f2bf(a[i]) | ((u32)f2bf(bv[i]) << 16);
    }
    __syncthreads();
#pragma unroll
    for (int pass = 0; pass < 2; ++pass) {
      const int v = pass * 256 + t;
      const int c = v >> 3, mg = v & 7;
      union { bf16x8 o; u32 q[4]; } u;
#pragma unroll
      for (int r = 0; r < 4; ++r) u.q[r] = LtT[c * 33 + mg * 4 + r];
      *(bf16x8*)&cwTb[(size_t)(c0 + c) * CC + m0 + mg * 8] = u.o;
    }
  } else {                            // bias_fuse
    const int o = (blk - 324) * 4 + (t >> 6);
    const int lane = t & 63;
    const float* wrow;
    float b0;
    if (o < CC) { wrow = wq + (size_t)o * CC;        b0 = bq[o]; }
    else        { wrow = wkv + (size_t)(o - CC) * CC; b0 = bkv[o - CC]; }
    float s = 0.f;
    for (int m = lane; m < CC; m += 64) s += wrow[m] * cb[m];
#pragma unroll
    for (int off = 32; off; off >>= 1) s += __shfl_xor(s, off, 64);
    if (lane == 0) bf_[o] = b0 + s;
  }
}

// ============================================================================
// trans_colsum: bid<27 -> weight GEMMs; 27..1562 -> transpose tiles
// (nt-fastest); 1563+ -> colsum partials.
// ============================================================================
__global__ __launch_bounds__(256)
void trans_colsum(const u16* __restrict__ xb, u16* __restrict__ xbT,
                  float* __restrict__ sxp, const u16* __restrict__ wtopb,
                  const u16* __restrict__ cwTb, u16* __restrict__ Wf,
                  u16* __restrict__ UvT) {
  __shared__ __align__(16) char smem[33280];
  const int bid = blockIdx.x;
  const int t = threadIdx.x;
  if (bid < 27) {                     // weight GEMMs: Wf = wtop@cw ; UvT
    u16* smemu = (u16*)smem;          // uses 32768 B
    int wb = bid;
    const u16 *A, *W; u16* C;
    if (wb < 18) { A = wtopb; W = cwTb; C = Wf; }
    else { wb -= 18; A = cwTb; W = wtopb + 2 * CC * CC; C = UvT; }
    const int bn = wb % 3, bm = wb / 3;
    const int wid = t >> 6, lane = t & 63;
    const int wr = wid >> 1, wc = wid & 1;
    const int row0 = bm * 128, col0 = bn * 128;
    const int lrow = lane & 15;
    const int lswz = (lane & 7) << 3;
    const int arow = t >> 3;
    const int scol = ((t & 7) ^ ((t >> 3) & 7)) * 8;
    const u16* Ag = A + (size_t)(row0 + arow) * CC + scol;
    const u16* Wg = W + (size_t)(col0 + arow) * CC + scol;
    u16* As = smemu;
    u16* Bs = smemu + 8192;
    f32x4 acc[4][4] = {};
    for (int kt = 0; kt < 6; ++kt) {
      __syncthreads();
      const int k0 = kt * 64;
#pragma unroll
      for (int it = 0; it < 4; ++it) {
        gload16(Ag + (size_t)(it * 32) * CC + k0, As + t * 8 + it * 2048);
        gload16(Wg + (size_t)(it * 32) * CC + k0, Bs + t * 8 + it * 2048);
      }
      __syncthreads();
#pragma unroll
      for (int kk = 0; kk < 2; ++kk) {
        const int lk = (kk * 32 + (lane >> 4) * 8) ^ lswz;
        bf16x8 af[4], bf4[4];
#pragma unroll
        for (int i = 0; i < 4; ++i)
          af[i] = *(const bf16x8*)&As[(wr * 64 + i * 16 + lrow) * 64 + lk];
#pragma unroll
        for (int j = 0; j < 4; ++j)
          bf4[j] = *(const bf16x8*)&Bs[(wc * 64 + j * 16 + lrow) * 64 + lk];
#pragma unroll
        for (int i = 0; i < 4; ++i)
#pragma unroll
          for (int j = 0; j < 4; ++j)
            acc[i][j] = __builtin_amdgcn_mfma_f32_16x16x32_bf16(af[i], bf4[j], acc[i][j], 0, 0, 0);
      }
    }
    const int lr = (lane >> 4) * 4;
#pragma unroll
    for (int i = 0; i < 4; ++i)
#pragma unroll
      for (int j = 0; j < 4; ++j) {
        const int ccol = col0 + wc * 64 + j * 16 + lrow;
#pragma unroll
        for (int r = 0; r < 4; ++r)
          C[(size_t)(row0 + wr * 64 + i * 16 + lr + r) * CC + ccol] =
              f2bf(acc[i][j][r]);
      }
    return;
  }
  if (bid < 1563) {                   // transpose tile (32c x 512n), nt-fastest
    u32* LtT = (u32*)smem;            // [32][260]
    const int tb = bid - 27;
    const int nt = tb % 8, ct = (tb / 8) % 12, b = tb / 96;
    const int n0 = nt * 512, c0 = ct * 32;
    const int coct = t & 3, c = coct * 8;
    const int q = t >> 2;
    const int swzw = coct << 3;
#pragma unroll
    for (int p = 0; p < 4; ++p) {
      const int npair = q + p * 64;
      const int n = 2 * npair;
      const u16* s0 = &xb[((size_t)(b * NN + n0 + n)) * CC + c0 + c];
      union { bf16x8 v; u16 e[8]; } ua, ub;
      ua.v = *(const bf16x8*)s0;
      ub.v = *(const bf16x8*)(s0 + CC);
      const int npw = npair ^ swzw;
#pragma unroll
      for (int i = 0; i < 8; ++i)
        LtT[(c + i) * 260 + npw] = (u32)ua.e[i] | ((u32)ub.e[i] << 16);
    }
    __syncthreads();
#pragma unroll
    for (int p = 0; p < 8; ++p) {
      const int id = p * 256 + t;
      const int cc2 = id >> 6, ng = id & 63;
      const int swz2 = ((cc2 >> 3) & 3) << 3;
      union { u32x4 q4; bf16x8 o; } u;
      u.q4 = *(const u32x4*)&LtT[cc2 * 260 + ((ng * 4) ^ swz2)];
      *(bf16x8*)&xbT[((size_t)(b * CC + c0 + cc2)) * NN + n0 + ng * 8] = u.o;
    }
  } else {                            // colsum partial over n-quarter p
    float (*red)[8] = (float(*)[8])smem;       // [256][8]
    const int k = bid - 1563;         // 0..383
    const int p = k & 3, k2 = k >> 2;
    const int c0 = (k2 % 6) * 64, b = k2 / 6;
    const int c8 = t & 7, ns = t >> 3;
    const u16* src = xb + (size_t)b * NN * CC + (size_t)(p * 1024) * CC +
                     c0 + c8 * 8;
    float a[8] = {};
    for (int it = 0; it < 32; ++it) {
      const bf16x8 v = *(const bf16x8*)(src + (size_t)(ns + 32 * it) * CC);
#pragma unroll
      for (int r = 0; r < 8; ++r) a[r] += bf2f((u16)v[r]);
    }
#pragma unroll
    for (int r = 0; r < 8; ++r) red[t][r] = a[r];
    __syncthreads();
    if (t < 64) {
      const int c8o = t >> 3, e = t & 7;
      float s = 0.f;
#pragma unroll
      for (int n2 = 0; n2 < 32; ++n2) s += red[c8o + 8 * n2][e];
      sxp[(size_t)(p * 16 + b) * CC + c0 + c8o * 8 + e] = s;
    }
  }
}

// ============================================================================
// proj_sx: P[b][o] = sum_c Wf[o][c] * (sum_p sxp[p][b][c]), o<768
// ============================================================================
__global__ __launch_bounds__(128)
void proj_sx(const u16* __restrict__ Wf, const float* __restrict__ sxp,
             float* __restrict__ P) {
  __shared__ float sl[CC];
  const int b = blockIdx.y, o = blockIdx.x * 128 + threadIdx.x;
  for (int i = threadIdx.x; i < CC; i += 128)
    sl[i] = sxp[(size_t)b * CC + i] + sxp[(size_t)(16 + b) * CC + i] +
            sxp[(size_t)(32 + b) * CC + i] + sxp[(size_t)(48 + b) * CC + i];
  __syncthreads();
  float acc = 0.f;
  const u16* wr = Wf + (size_t)o * CC;
  for (int c8 = 0; c8 < CC; c8 += 8) {
    const bf16x8 w = *(const bf16x8*)(wr + c8);
#pragma unroll
    for (int r = 0; r < 8; ++r) acc += bf2f((u16)w[r]) * sl[c8 + r];
  }
  P[b * 768 + o] = acc;
}

// ============================================================================
// Generic GEMM: C[M,N](+p partials) = A[M,K-slice] @ W[N,K-slice]^T (+bias)
// 512 threads / 8 waves (wave 64x32), dbuf issue-early/wait-late, T2 swizzle.
// TRI: 6 upper tiles. SWZ: XCD swizzle. ORD=1: bm-fastest (W-panel L2 reuse).
// ============================================================================
template<typename OT, int BIASMODE, int TRI = 0, int SWZ = 1, int ORD = 0>
__global__ __launch_bounds__(512)
void gemm_f(const u16* __restrict__ A, const u16* __restrict__ W,
            const float* __restrict__ bias, OT* __restrict__ C,
            int M, int N, int K, int klen, int nbn, int nbm, int tpb,
            long sA, long sW, long sC, long sCp, long sBias) {
  constexpr int BK = 64;
  __shared__ __align__(16) u16 smem[32768];   // 64 KB: 2 x (As 8192 | Bs 8192)

  const int nx = gridDim.x;
  const int lin = blockIdx.x;
  const int lin2 = SWZ ? (lin & 7) * (nx >> 3) + (lin >> 3) : lin;
  const int b = lin2 / tpb;
  int t2 = lin2 % tpb;
  int bn, bm, p;
  if constexpr (TRI) {
    const int tl = t2 % 6; p = t2 / 6;
    bm = tl < 3 ? 0 : (tl < 5 ? 1 : 2);
    bn = tl < 3 ? tl : (tl < 5 ? tl - 2 : 2);
  } else if constexpr (ORD) {
    bm = t2 % nbm; t2 /= nbm;
    bn = t2 % nbn;
    p = t2 / nbn;
  } else {
    bn = t2 % nbn; t2 /= nbn;
    bm = t2 % nbm;
    p = t2 / nbm;
  }
  A += (size_t)b * sA; W += (size_t)b * sW;
  C += (size_t)b * sC + (size_t)p * sCp;
  if (BIASMODE) bias += (size_t)b * sBias;

  const int t = threadIdx.x;
  const int wid = t >> 6, lane = t & 63;
  const int wr = wid >> 2, wc = wid & 3;        // 2 x 4 wave grid, 64x32 each
  const int row0 = bm * 128, col0 = bn * 128;
  const int lrow = lane & 15;
  const int lswz = (lane & 7) << 3;
  const int kstart = p * klen;

  const int arow = t >> 3;                       // 0..63
  const int scol = ((t & 7) ^ ((t >> 3) & 7)) * 8;   // inverse-swizzled source
  const u16* Ag = A + (size_t)(row0 + arow) * K + scol;
  const u16* Wg = W + (size_t)(col0 + arow) * K + scol;

  f32x4 acc[4][2] = {};
  const int NT = klen >> 6;

  auto stage = [&](int buf, int kt) {
    u16* Al = smem + buf * 16384 + t * 8;
    u16* Bl = smem + buf * 16384 + 8192 + t * 8;
    const int k0 = kstart + kt * BK;
#pragma unroll
    for (int it = 0; it < 2; ++it) {
      gload16(Ag + (size_t)(it * 64) * K + k0, Al + it * 4096);
      gload16(Wg + (size_t)(it * 64) * K + k0, Bl + it * 4096);
    }
  };

  stage(0, 0);
  __syncthreads();                 // drain tile 0
  int cur = 0;
  for (int kt = 0; kt < NT; ++kt) {
    if (kt + 1 < NT) stage(cur ^ 1, kt + 1);     // issue-early (overlaps MFMA)
    const u16* As = smem + cur * 16384;
    const u16* Bs = smem + cur * 16384 + 8192;
#pragma unroll
    for (int kk = 0; kk < 2; ++kk) {
      const int lk = (kk * 32 + (lane >> 4) * 8) ^ lswz;
      bf16x8 af[4], bfv[2];
#pragma unroll
      for (int i = 0; i < 4; ++i)
        af[i] = *(const bf16x8*)&As[(wr * 64 + i * 16 + lrow) * BK + lk];
#pragma unroll
      for (int j = 0; j < 2; ++j)
        bfv[j] = *(const bf16x8*)&Bs[(wc * 32 + j * 16 + lrow) * BK + lk];
#pragma unroll
      for (int i = 0; i < 4; ++i)
#pragma unroll
        for (int j = 0; j < 2; ++j)
          acc[i][j] = __builtin_amdgcn_mfma_f32_16x16x32_bf16(af[i], bfv[j], acc[i][j], 0, 0, 0);
    }
    __syncthreads();               // wait-late: drains next tile's loads + LDS reads
    cur ^= 1;
  }

  const int lr = (lane >> 4) * 4;
  if constexpr (sizeof(OT) == 2) {
    u16* Ct = smem;                 // [128][132] bf16 = 33792 B
#pragma unroll
    for (int i = 0; i < 4; ++i)
#pragma unroll
      for (int j = 0; j < 2; ++j) {
        const int ccol = wc * 32 + j * 16 + lrow;
        float bv = 0.f;
        if constexpr (BIASMODE == 1) bv = bias[col0 + ccol];
#pragma unroll
        for (int r = 0; r < 4; ++r) {
          const int rrow = wr * 64 + i * 16 + lr + r;
          float b2 = bv;
          if constexpr (BIASMODE == 2) b2 = bias[row0 + rrow];
          Ct[rrow * 132 + ccol] = f2bf(acc[i][j][r] + b2);
        }
      }
    __syncthreads();
#pragma unroll
    for (int it = 0; it < 4; ++it) {
      const int id = it * 512 + t;
      const int row = id >> 4, c16 = (id & 15) * 8;
      *(bf16x8*)((u16*)C + (size_t)(row0 + row) * N + col0 + c16) =
          *(const bf16x8*)&Ct[row * 132 + c16];
    }
  } else {
    const int orow = row0 + wr * 64, ocol = col0 + wc * 32;
#pragma unroll
    for (int i = 0; i < 4; ++i)
#pragma unroll
      for (int j = 0; j < 2; ++j) {
        const int cc2 = ocol + j * 16 + lrow;
        float bv = 0.f;
        if constexpr (BIASMODE == 1) bv = bias[cc2];
#pragma unroll
        for (int r = 0; r < 4; ++r) {
          const int rr = orow + i * 16 + lr + r;
          float b2 = bv;
          if constexpr (BIASMODE == 2) b2 = bias[rr];
          C[(size_t)rr * N + cc2] = acc[i][j][r] + b2;
        }
      }
  }
}

// ============================================================================
// reduceG v2 (tiled, fully coalesced): Gbf[b][i][j] = bf16(sum_p Gpart upper).
// ============================================================================
__global__ __launch_bounds__(256)
void reduceG(const float* __restrict__ Gp, u16* __restrict__ Gbf) {
  __shared__ float lt[64 * 65];       // 16640 B
  const int b = blockIdx.y;
  const int tile = blockIdx.x;        // 0..35
  const int ti = tile / 6, tj = tile % 6;
  const bool mir = (ti >> 1) > (tj >> 1);      // strictly-lower 128-tile
  const int si = mir ? tj : ti, sj = mir ? ti : tj;
  const float* src = Gp + (size_t)b * 4 * 147456;
  u16* dst = Gbf + (size_t)b * 147456;
  const int t = threadIdx.x;
  const int r4 = t >> 4, c4 = (t & 15) * 4;
#pragma unroll
  for (int pass = 0; pass < 4; ++pass) {
    const int r = pass * 16 + r4;
    const size_t off = (size_t)(si * 64 + r) * CC + sj * 64 + c4;
    f32x4 s = *(const f32x4*)(src + off);
    s += *(const f32x4*)(src + 147456 + off);
    s += *(const f32x4*)(src + 2 * 147456 + off);
    s += *(const f32x4*)(src + 3 * 147456 + off);
    if (!mir) {
      union { u64 q; u16 e[4]; } o;
      o.e[0] = f2bf(s[0]); o.e[1] = f2bf(s[1]);
      o.e[2] = f2bf(s[2]); o.e[3] = f2bf(s[3]);
      *(u64*)&dst[(size_t)(ti * 64 + r) * CC + tj * 64 + c4] = o.q;
    } else {
#pragma unroll
      for (int k = 0; k < 4; ++k) lt[r * 65 + c4 + k] = s[k];
    }
  }
  if (mir) {
    __syncthreads();
#pragma unroll
    for (int pass = 0; pass < 4; ++pass) {
      const int i = pass * 16 + r4;
      union { u64 q; u16 e[4]; } o;
#pragma unroll
      for (int k = 0; k < 4; ++k) o.e[k] = f2bf(lt[(c4 + k) * 65 + i]);
      *(u64*)&dst[(size_t)(ti * 64 + i) * CC + tj * 64 + c4] = o.q;
    }
  }
}

// ============================================================================
// s_softmax: per (b,h): S = M1_h @ Uk_h^T + rank-1 terms, *N^-0.5, softmax;
// AU = attn @ Uv_h -> AUb rows (i*8+h); rbias = attn @ bv'
// ============================================================================
__global__ __launch_bounds__(256)
void s_softmax(const u16* __restrict__ M1g, const u16* __restrict__ Wf,
               const float* __restrict__ bf_, const float* __restrict__ P,
               const u16* __restrict__ UvT, u16* __restrict__ AUb,
               float* __restrict__ rbias) {
  __shared__ float Sf[48 * 52];
  __shared__ __align__(16) u16 att[48 * 56];
  const int bh = blockIdx.x, b = bh >> 3, h = bh & 7;
  const int t = threadIdx.x, wid = t >> 6, lane = t & 63;
  const int lrow = lane & 15, lkq = lane >> 4;

  if (wid < 3) {
    f32x4 acc[3] = {};
    const u16* Arow = M1g + (size_t)b * 147456 + (size_t)(h * 48 + wid * 16 + lrow) * CC;
    const u16* Brow = Wf + (size_t)(CC + h * 48) * CC;    // Uk
    for (int ks = 0; ks < 12; ++ks) {
      const int k = ks * 32 + lkq * 8;
      const bf16x8 af = *(const bf16x8*)(Arow + k);
#pragma unroll
      for (int j = 0; j < 3; ++j) {
        const bf16x8 bfr = *(const bf16x8*)(Brow + (size_t)(j * 16 + lrow) * CC + k);
        acc[j] = __builtin_amdgcn_mfma_f32_16x16x32_bf16(af, bfr, acc[j], 0, 0, 0);
      }
    }
    const int lr = lkq * 4;
#pragma unroll
    for (int j = 0; j < 3; ++j)
#pragma unroll
      for (int r = 0; r < 4; ++r)
        Sf[(wid * 16 + lr + r) * 52 + j * 16 + lrow] = acc[j][r];
  }
  __syncthreads();

  if (t < 48) {
    const float bi = bf_[h * 48 + t];
    const float pq = P[b * 768 + h * 48 + t];
    float row[48];
    float mx = -1e30f;
#pragma unroll
    for (int j = 0; j < 48; ++j) {
      const float g = bf_[CC + h * 48 + j];
      const float pk = P[b * 768 + CC + h * 48 + j];
      const float s = (Sf[t * 52 + j] + bi * pk + pq * g + 4096.f * bi * g) * 0.015625f;
      row[j] = s;
      mx = fmaxf(mx, s);
    }
    float sum = 0.f;
#pragma unroll
    for (int j = 0; j < 48; ++j) { row[j] = __expf(row[j] - mx); sum += row[j]; }
    const float inv = 1.f / sum;
    float rb = 0.f;
#pragma unroll
    for (int j = 0; j < 48; ++j) {
      const float a = row[j] * inv;
      att[t * 56 + j] = f2bf(a);
      rb += a * bf_[2 * CC + h * 48 + j];
    }
#pragma unroll
    for (int j = 48; j < 56; ++j) att[t * 56 + j] = 0;
    rbias[b * CC + t * 8 + h] = rb;
  }
  __syncthreads();

  f32x4 acc[3][6] = {};
  const u16* Vbase = UvT + h * 48;
  const bf16x8 z = {};
#pragma unroll
  for (int kk = 0; kk < 2; ++kk) {
    const int k = kk * 32 + lkq * 8;
    bf16x8 af[3];
#pragma unroll
    for (int i = 0; i < 3; ++i) {
      af[i] = *(const bf16x8*)&att[(i * 16 + lrow) * 56 + k];
      if (k >= 48) af[i] = z;
    }
#pragma unroll
    for (int ct = 0; ct < 6; ++ct) {
      const int c = wid * 96 + ct * 16 + lrow;
      bf16x8 bfr = *(const bf16x8*)(Vbase + (size_t)c * CC + k);
      if (k >= 48) bfr = z;
#pragma unroll
      for (int i = 0; i < 3; ++i)
        acc[i][ct] = __builtin_amdgcn_mfma_f32_16x16x32_bf16(af[i], bfr, acc[i][ct], 0, 0, 0);
    }
  }
  const int lr = lkq * 4;
#pragma unroll
  for (int i = 0; i < 3; ++i)
#pragma unroll
    for (int ct = 0; ct < 6; ++ct) {
      const int c = wid * 96 + ct * 16 + lrow;
#pragma unroll
      for (int r = 0; r < 4; ++r) {
        const int ii = i * 16 + lr + r;
        AUb[(size_t)b * 147456 + (size_t)(ii * 8 + h) * CC + c] = f2bf(acc[i][ct][r]);
      }
    }
}

// ============================================================================
extern "C" void kernel_launch(void* const* d_in, const int* in_sizes, int n_in,
                              void* d_out, int out_size, void* d_ws, size_t ws_size,
                              hipStream_t stream) {
  const float* x      = (const float*)d_in[0];
  const float* conv_w = (const float*)d_in[1];
  const float* conv_b = (const float*)d_in[2];
  const float* wq     = (const float*)d_in[3];
  const float* bq     = (const float*)d_in[4];
  const float* wkv    = (const float*)d_in[5];
  const float* bkv    = (const float*)d_in[6];
  const float* wp     = (const float*)d_in[7];
  const float* bp     = (const float*)d_in[8];
  float* y = (float*)d_out;

  char* ws = (char*)d_ws;
  u16*   Wf    = (u16*)(ws + 0);              //   884,736 (rows 768+ unused)
  float* bf_   = (float*)(ws + 884736);       //     4,608
  u16*   wpb   = (u16*)(ws + 889344);         //   294,912
  u16*   UvT   = (u16*)(ws + 1184256);        //   294,912
  float* P     = (float*)(ws + 1503744);      //    49,152
  float* rb    = (float*)(ws + 1552896);      //    24,576
  u16*   M1g   = (u16*)(ws + 1577472);        // 4,718,592
  u16*   Gbf   = (u16*)(ws + 6296064);        // 4,718,592
  u16*   AUb   = (u16*)(ws + 11014656);       // 4,718,592
  float* Gpart = (float*)(ws + 15733248);     // 37,748,736
  float* sxp   = Gpart;                       // 98,304 (dead before gram)
  u16*   wtopb = (u16*)(ws + 53481984);       //   884,736  [wq;wkv] bf16
  u16*   cwTb  = (u16*)(ws + 54366720);       //   294,912  cw^T bf16
  u16*   xb    = (u16*)(ws + 54661632);       // 50,331,648
  u16*   xbT   = (u16*)(ws + 104993280);      // 50,331,648 (dead after gram)
  u16*   R     = xbT;                         // aliases xbT
  // total ws use: 155,324,928 B

  // K1: x->bf16 + all weight prep (merged)
  conv_fused<<<dim3(3684), dim3(256), 0, stream>>>(
      x, xb, wp, wq, wkv, conv_w, bq, bkv, conv_b, wpb, wtopb, cwTb, bf_);
  // K2: weight GEMMs (27) + xb transpose (1536, nt-fastest) + colsum (384)
  trans_colsum<<<dim3(1947), dim3(256), 0, stream>>>(
      xb, xbT, sxp, wtopb, cwTb, Wf, UvT);
  // K3: P projections
  proj_sx<<<dim3(6, 16), dim3(128), 0, stream>>>(Wf, sxp, P);
  // K4: Gram partials (symmetric: 6 upper tiles), split-K 4
  gemm_f<float, 0, 1><<<dim3(384), dim3(512), 0, stream>>>(
      xbT, xbT, nullptr, Gpart, CC, CC, NN, 1024, 3, 3, 24,
      (long)CC * NN, (long)CC * NN, 4L * 147456, 147456, 0);
  // K5: reduce + mirror
  reduceG<<<dim3(36, 16), dim3(256), 0, stream>>>(Gpart, Gbf);
  // K6: M1g[b] = Uq @ Gx_b
  gemm_f<u16, 0><<<dim3(144), dim3(512), 0, stream>>>(
      Wf, Gbf, nullptr, M1g, CC, CC, CC, CC, 3, 3, 9,
      0, 147456, 147456, 0, 0);
  // K7: S + softmax + AU
  s_softmax<<<dim3(128), dim3(256), 0, stream>>>(M1g, Wf, bf_, P, UvT, AUb, rb);
  // K8: R[b] = AUb[b] @ xb_b^T + rbias; ORD=1: the 3 blocks sharing an xb
  // W-panel are lin2-consecutive -> same XCD -> panel L2 reuse
  gemm_f<u16, 2, 0, 1, 1><<<dim3(1536), dim3(512), 0, stream>>>(
      AUb, xb, rb, R, CC, NN, CC, CC, 32, 3, 96,
      147456, (long)NN * CC, (long)NN * CC, 0, CC);
  // K9: y = R @ wpb^T + bp
  gemm_f<float, 1><<<dim3(1536), dim3(512), 0, stream>>>(
      R, wpb, bp, y, BB * NN, CC, CC, CC, 3, 512, 1536,
      0, 0, 0, 0, 0);
}